// Round 5
// baseline (230.558 us; speedup 1.0000x reference)
//
#include <hip/hip_runtime.h>
#include <hip/hip_bf16.h>

typedef __hip_bfloat16 bf16;
typedef __attribute__((ext_vector_type(8))) short short8;   // 8 bf16 = 16B
typedef __attribute__((ext_vector_type(4))) float f32x4;
typedef unsigned short u16;

#define N_NODES 50000
#define NE      800000
#define DIN     128
#define DH      128
#define DOUT    64
#define MTILES  (N_NODES / 16)    // 3125, exact
#define CAP     64                // padded-CSR slots/node; deg~Poisson(16), P(deg>=64)~e^-23 per node
#define DSTRIDE 8                 // deg counter stride in ints: 4 nodes per 128B line
#define NXCD    8
#define NPX     (N_NODES / NXCD)  // 6250 nodes per XCD
#define ECHUNK  2048              // edges per chunk (256 thr * 8)
#define NCHUNK  ((NE + ECHUNK - 1) / ECHUNK)   // 391
#define SCAT_BLKS (NCHUNK * NXCD)              // 3128

__device__ __forceinline__ int clamp_node(int s) {
    return min(max(s, 0), N_NODES - 1);   // poison-robust: real data always in range
}
__device__ __forceinline__ float b2f(short s) {
    unsigned u = ((unsigned)(unsigned short)s) << 16;
    float f; __builtin_memcpy(&f, &u, 4); return f;
}
__device__ __forceinline__ short f2b(float f) {
    __hip_bfloat16 h = __float2bfloat16(f);
    short s; __builtin_memcpy(&s, &h, 2); return s;
}

// ---------------- fused build: XCD-local padded ushort CSR + bf16 cvt ----------------
// Scatter phase: block (chunk, xcd=blockIdx&7) reads its 2048-edge chunk and handles ONLY
// dsts in [xcd*NPX, (xcd+1)*NPX). blockIdx%8 ~ XCD (dispatch round-robin) => deg/csr lines
// are single-XCD: atomics hit locally-owned L2 lines, each line written back to HBM once.
__global__ void k_build(const int* __restrict__ src, const int* __restrict__ dst,
                        int* __restrict__ degPad, u16* __restrict__ csrPad,
                        const float* __restrict__ x, __hip_bfloat162* __restrict__ xb2,
                        const float* __restrict__ W1l, const float* __restrict__ W1r,
                        const float* __restrict__ W2l, const float* __restrict__ W2r,
                        bf16* __restrict__ W1b, bf16* __restrict__ W2b) {
    int b = blockIdx.x;
    if (b < SCAT_BLKS) {
        int chunk = b >> 3;
        int lo = (b & 7) * NPX, hi = lo + NPX;
        int e0 = chunk * ECHUNK + threadIdx.x * 8;
        if (e0 + 7 < NE) {                        // 8 | NE: per-thread all-or-nothing
            int4 d0 = *(const int4*)(dst + e0);
            int4 d1 = *(const int4*)(dst + e0 + 4);
            int4 s0 = *(const int4*)(src + e0);
            int4 s1 = *(const int4*)(src + e0 + 4);
            int dv[8] = {d0.x, d0.y, d0.z, d0.w, d1.x, d1.y, d1.z, d1.w};
            int sv[8] = {s0.x, s0.y, s0.z, s0.w, s1.x, s1.y, s1.z, s1.w};
            #pragma unroll
            for (int j = 0; j < 8; ++j) {
                int t = dv[j];
                if (t >= lo && t < hi) {          // XCD-range filter (also poison filter)
                    int pos = atomicAdd(&degPad[t * DSTRIDE], 1);
                    if (pos < CAP) csrPad[t * CAP + pos] = (u16)sv[j];
                }
            }
        }
    } else if (b < SCAT_BLKS + 6250) {            // N*DIN/4 = 1.6M float4 groups exactly
        int i = (b - SCAT_BLKS) * 256 + threadIdx.x;
        float4 v = ((const float4*)x)[i];
        __hip_bfloat162 a, bb;
        a.x = __float2bfloat16(v.x); a.y = __float2bfloat16(v.y);
        bb.x = __float2bfloat16(v.z); bb.y = __float2bfloat16(v.w);
        xb2[2 * i]     = a;
        xb2[2 * i + 1] = bb;
    } else {                                      // 192 blocks: 32768 + 16384 weights exactly
        int i = (b - SCAT_BLKS - 6250) * 256 + threadIdx.x;
        if (i < 128 * 256) {
            int n = i >> 8, k = i & 255;
            float v = (k < 128) ? W1l[n * 128 + k] : W1r[n * 128 + (k - 128)];
            W1b[i] = __float2bfloat16(v);
        } else {
            int j = i - 128 * 256;
            int n = j >> 7, k = j & 127;
            float v = (n < 64) ? W2l[n * 128 + k] : W2r[(n - 64) * 128 + k];
            W2b[j] = __float2bfloat16(v);
        }
    }
}

// ---------------- fused layer-1 v2: 1024 threads, 1 node per wave (restores 50K-wave MLP) ----------------
// 16 waves/block. Agg: wave w aggregates node mt*16+w with round-3's batched-gather structure,
// mean row -> LDS ms. GEMM split by wave group: waves 0-7 own one 16-col fragment of GEMM1
// (8 MFMAs, K=256 over [ms|xb]); waves 8-15 preload W2 fragments (overlaps GEMM1) and own
// GEMM2 (4 MFMAs, K=128 from hs) + the pb/qbuf writes.
__global__ __launch_bounds__(1024) void k_fused1(const int* __restrict__ degPad,
                                                 const u16* __restrict__ csrPad,
                                                 const short* __restrict__ xb,
                                                 const short* __restrict__ W1b,
                                                 const float* __restrict__ b1,
                                                 const short* __restrict__ W2b,
                                                 bf16* __restrict__ pb,
                                                 float* __restrict__ qbuf) {
    __shared__ short ms[16][136];                 // aggregated-mean tile (bf16), +8 pad
    __shared__ short hs[16][136];                 // h tile after relu, +8 pad
    int wave = threadIdx.x >> 6, lane = threadIdx.x & 63;
    int q = lane >> 4, mr = lane & 15;            // GEMM roles
    int g = q, c = mr;                            // agg roles: g = neighbor slot (0-3), c = 16B chunk (0-15)
    int mt = blockIdx.x;
    // ---- Phase A: each wave aggregates ONE node (row = wave) ----
    {
        int row = wave;
        int node = mt * 16 + row;
        int d = min(max(degPad[node * DSTRIDE], 0), CAP);   // poison-robust, wave-uniform
        const u16* crow = csrPad + node * CAP;
        int idx[8];                               // slots g, 4+g, ..., 28+g (covers d<=32)
        #pragma unroll
        for (int t = 0; t < 8; ++t) idx[t] = crow[t * 4 + g];
        float acc[8];
        #pragma unroll
        for (int j = 0; j < 8; ++j) acc[j] = 0.f;
        short8 v[8];
        #pragma unroll
        for (int t = 0; t < 8; ++t) {             // issue ALL gathers before any accumulate
            if (4 * t < d) {
                int n = clamp_node(idx[t]);
                v[t] = *(const short8*)(xb + (size_t)n * DIN + c * 8);
            }
        }
        #pragma unroll
        for (int t = 0; t < 8; ++t) {
            if (4 * t < d) {
                if (4 * t + g < d) {              // per-lane valid only in final group
                    #pragma unroll
                    for (int j = 0; j < 8; ++j) acc[j] += b2f(v[t][j]);
                }
            }
        }
        if (d > 32) {                             // rare (P ~ 1e-4), wave-uniform
            int idxh[8];
            #pragma unroll
            for (int t = 8; t < 16; ++t) idxh[t - 8] = crow[t * 4 + g];
            short8 vh[8];
            #pragma unroll
            for (int t = 8; t < 16; ++t) {
                if (4 * t < d) {
                    int n = clamp_node(idxh[t - 8]);
                    vh[t - 8] = *(const short8*)(xb + (size_t)n * DIN + c * 8);
                }
            }
            #pragma unroll
            for (int t = 8; t < 16; ++t) {
                if (4 * t < d) {
                    if (4 * t + g < d) {
                        #pragma unroll
                        for (int j = 0; j < 8; ++j) acc[j] += b2f(vh[t - 8][j]);
                    }
                }
            }
        }
        #pragma unroll
        for (int j = 0; j < 8; ++j) {             // reduce across the 4 neighbor slots
            acc[j] += __shfl_xor(acc[j], 16);
            acc[j] += __shfl_xor(acc[j], 32);
        }
        if (g == 0) {
            float inv = (d > 0) ? 1.0f / (float)d : 0.0f;
            short8 o;
            #pragma unroll
            for (int j = 0; j < 8; ++j) o[j] = f2b(acc[j] * inv);
            *(short8*)(&ms[row][c * 8]) = o;
        }
    }
    // ---- weight/A fragment loads, split by wave group (issued before barrier: overlap agg tails) ----
    int n0 = (wave & 7) * 16;                     // 16-col fragment base for this wave
    short8 Bf1[8], Af[8], Bf2[4];
    float bias0 = 0.f;
    if (wave < 8) {
        const short* wrow = W1b + (size_t)(n0 + mr) * 256 + q * 8;
        #pragma unroll
        for (int ks = 0; ks < 8; ++ks) Bf1[ks] = *(const short8*)(wrow + ks * 32);
        bias0 = b1[n0 + mr];
        const short* a1 = xb + (size_t)(mt * 16 + mr) * DIN + q * 8;
        #pragma unroll
        for (int ks = 0; ks < 4; ++ks) Af[4 + ks] = *(const short8*)(a1 + ks * 32);
    } else {
        const short* wrow = W2b + (size_t)(n0 + mr) * 128 + q * 8;
        #pragma unroll
        for (int ks = 0; ks < 4; ++ks) Bf2[ks] = *(const short8*)(wrow + ks * 32);
    }
    __syncthreads();                              // ms tile complete
    // ---- GEMM1 (waves 0-7): 16 rows x 16 cols, K=256 over [ms|xb] ----
    if (wave < 8) {
        #pragma unroll
        for (int ks = 0; ks < 4; ++ks) Af[ks] = *(const short8*)(&ms[mr][ks * 32 + q * 8]);
        f32x4 acc0 = {0.f, 0.f, 0.f, 0.f};
        #pragma unroll
        for (int ks = 0; ks < 8; ++ks)
            acc0 = __builtin_amdgcn_mfma_f32_16x16x32_bf16(Af[ks], Bf1[ks], acc0, 0, 0, 0);
        #pragma unroll
        for (int r = 0; r < 4; ++r) {             // bias + relu, stage h tile to LDS (C/D layout)
            float v0 = acc0[r] + bias0;
            hs[q * 4 + r][n0 + mr] = f2b(v0 > 0.f ? v0 : 0.f);
        }
    }
    __syncthreads();                              // hs tile complete
    // ---- GEMM2 (waves 8-15): A from LDS (row mr, 16B contiguous), K=128 ----
    if (wave >= 8) {
        short8 Ah[4];
        #pragma unroll
        for (int ks = 0; ks < 4; ++ks) Ah[ks] = *(const short8*)(&hs[mr][ks * 32 + q * 8]);
        f32x4 c20 = {0.f, 0.f, 0.f, 0.f};
        #pragma unroll
        for (int ks = 0; ks < 4; ++ks)
            c20 = __builtin_amdgcn_mfma_f32_16x16x32_bf16(Ah[ks], Bf2[ks], c20, 0, 0, 0);
        // cols: waves 8-11 -> pb (0-63) bf16; waves 12-15 -> qbuf (64-127) fp32. Wave-uniform.
        #pragma unroll
        for (int r = 0; r < 4; ++r) {
            int row = mt * 16 + q * 4 + r;
            int c0 = n0 + mr;
            if (n0 < 64) {
                pb[(size_t)row * 64 + c0] = __float2bfloat16(c20[r]);
            } else {
                qbuf[(size_t)row * 64 + (c0 - 64)] = c20[r];
            }
        }
    }
}

// ---------------- layer-2 aggregation + epilogue: index-prefetch + batched gathers ----------------
// lane = g*8 + c : g = neighbor slot (0-7), c = 16B chunk (0-7) of the 128B pb row.
__global__ __launch_bounds__(256) void k_agg2f(const int* __restrict__ degPad, const u16* __restrict__ csrPad,
                                               const short* __restrict__ pb, const float* __restrict__ qbuf,
                                               const float* __restrict__ b2, float* __restrict__ out) {
    int node = blockIdx.x * 4 + (threadIdx.x >> 6);
    if (node >= N_NODES) return;
    int lane = threadIdx.x & 63;
    int g = lane >> 3, c = lane & 7;
    int d = min(max(degPad[node * DSTRIDE], 0), CAP);   // poison-robust
    const u16* crow = csrPad + node * CAP;
    int idx[4];                                   // slots g, 8+g, 16+g, 24+g (covers d<=32)
    #pragma unroll
    for (int t = 0; t < 4; ++t) idx[t] = crow[t * 8 + g];
    float acc[8];
    #pragma unroll
    for (int j = 0; j < 8; ++j) acc[j] = 0.f;
    short8 v[4];
    #pragma unroll
    for (int t = 0; t < 4; ++t) {                 // issue ALL gathers before any accumulate
        if (8 * t < d) {
            int n = clamp_node(idx[t]);
            v[t] = *(const short8*)(pb + (size_t)n * 64 + c * 8);
        }
    }
    #pragma unroll
    for (int t = 0; t < 4; ++t) {
        if (8 * t < d) {
            if (8 * t + g < d) {                  // per-lane valid only in final group
                #pragma unroll
                for (int j = 0; j < 8; ++j) acc[j] += b2f(v[t][j]);
            }
        }
    }
    if (d > 32) {                                 // rare, wave-uniform
        int idxh[4];
        #pragma unroll
        for (int t = 4; t < 8; ++t) idxh[t - 4] = crow[t * 8 + g];
        short8 vh[4];
        #pragma unroll
        for (int t = 4; t < 8; ++t) {
            if (8 * t < d) {
                int n = clamp_node(idxh[t - 4]);
                vh[t - 4] = *(const short8*)(pb + (size_t)n * 64 + c * 8);
            }
        }
        #pragma unroll
        for (int t = 4; t < 8; ++t) {
            if (8 * t < d) {
                if (8 * t + g < d) {
                    #pragma unroll
                    for (int j = 0; j < 8; ++j) acc[j] += b2f(vh[t - 4][j]);
                }
            }
        }
    }
    #pragma unroll
    for (int j = 0; j < 8; ++j) {                 // reduce across the 8 neighbor slots
        acc[j] += __shfl_xor(acc[j], 8);
        acc[j] += __shfl_xor(acc[j], 16);
        acc[j] += __shfl_xor(acc[j], 32);
    }
    if (g == 0) {
        float inv = (d > 0) ? 1.0f / (float)d : 0.0f;
        const float* qr = qbuf + (size_t)node * 64 + c * 8;
        const float* br = b2 + c * 8;
        float* orow = out + (size_t)node * 64 + c * 8;
        float4 o0, o1;
        o0.x = acc[0] * inv + qr[0] + br[0];
        o0.y = acc[1] * inv + qr[1] + br[1];
        o0.z = acc[2] * inv + qr[2] + br[2];
        o0.w = acc[3] * inv + qr[3] + br[3];
        o1.x = acc[4] * inv + qr[4] + br[4];
        o1.y = acc[5] * inv + qr[5] + br[5];
        o1.z = acc[6] * inv + qr[6] + br[6];
        o1.w = acc[7] * inv + qr[7] + br[7];
        ((float4*)orow)[0] = o0;
        ((float4*)orow)[1] = o1;
    }
}

extern "C" void kernel_launch(void* const* d_in, const int* in_sizes, int n_in,
                              void* d_out, int out_size, void* d_ws, size_t ws_size,
                              hipStream_t stream) {
    const float* x   = (const float*)d_in[0];
    const int*   ei  = (const int*)  d_in[1];
    const float* W1l = (const float*)d_in[2];
    const float* b1  = (const float*)d_in[3];
    const float* W1r = (const float*)d_in[4];
    const float* W2l = (const float*)d_in[5];
    const float* b2  = (const float*)d_in[6];
    const float* W2r = (const float*)d_in[7];
    float* out = (float*)d_out;

    const int* src = ei;        // edge_index[0]
    const int* dst = ei + NE;   // edge_index[1]

    // workspace layout (bytes), ~40.1 MB (msg buffer eliminated by fusion):
    //   [0, 1600000)            degPad (N*8 ints, 4 nodes per 128B line)
    //   [1600000, 8000000)      csrPad (N*64 ushort)
    //   [8000000, 20800000)     xb  bf16 (N*128*2)
    //   [20800000, 27200000)    pb  bf16 (N*64*2)
    //   [27200000, 40000000)    qbuf fp32 (N*64*4)
    //   [40000000, 40065536)    W1b bf16 (128*256*2)
    //   [40065536, 40098304)    W2b bf16 (128*128*2)
    char* ws = (char*)d_ws;
    int*   degPad = (int*)  (ws + 0);
    u16*   csrPad = (u16*)  (ws + 1600000);
    short* xb     = (short*)(ws + 8000000);
    bf16*  pb     = (bf16*) (ws + 20800000);
    float* qbuf   = (float*)(ws + 27200000);
    bf16*  W1b    = (bf16*) (ws + 40000000);
    bf16*  W2b    = (bf16*) (ws + 40065536);

    hipMemsetAsync(degPad, 0, 1600000, stream);

    k_build<<<SCAT_BLKS + 6250 + 192, 256, 0, stream>>>(src, dst, degPad, csrPad,
                                                        x, (__hip_bfloat162*)xb,
                                                        W1l, W1r, W2l, W2r, W1b, W2b);
    k_fused1<<<MTILES, 1024, 0, stream>>>(degPad, csrPad, xb, (const short*)W1b, b1,
                                          (const short*)W2b, pb, qbuf);
    k_agg2f<<<(N_NODES + 3) / 4, 256, 0, stream>>>(degPad, csrPad, (const short*)pb, qbuf, b2, out);
}

// Round 6
// 187.819 us; speedup vs baseline: 1.2276x; 1.2276x over previous
//
#include <hip/hip_runtime.h>
#include <hip/hip_bf16.h>

typedef __hip_bfloat16 bf16;
typedef __attribute__((ext_vector_type(8))) short short8;   // 8 bf16 = 16B
typedef __attribute__((ext_vector_type(4))) float f32x4;
typedef unsigned short u16;

#define N_NODES 50000
#define NE      800000
#define DIN     128
#define DH      128
#define DOUT    64
#define MTILES  (N_NODES / 16)    // 3125, exact
#define CAP     64                // padded-CSR slots/node; deg~Poisson(16), P(deg>=64)~e^-23 per node
#define DSTRIDE 8                 // deg counter stride in ints: 4 nodes per 128B line
#define NXCD    8
#define NPX     (N_NODES / NXCD)  // 6250 nodes per XCD
#define ECHUNK  2048              // edges per chunk (256 thr * 8)
#define NCHUNK  ((NE + ECHUNK - 1) / ECHUNK)   // 391
#define SCAT_BLKS (NCHUNK * NXCD)              // 3128

__device__ __forceinline__ int clamp_node(int s) {
    return min(max(s, 0), N_NODES - 1);   // poison-robust: real data always in range
}
__device__ __forceinline__ float b2f(short s) {
    unsigned u = ((unsigned)(unsigned short)s) << 16;
    float f; __builtin_memcpy(&f, &u, 4); return f;
}
__device__ __forceinline__ short f2b(float f) {
    __hip_bfloat16 h = __float2bfloat16(f);
    short s; __builtin_memcpy(&s, &h, 2); return s;
}

// ---------------- fused build: XCD-local padded ushort CSR + bf16 cvt ----------------
// Scatter phase: block (chunk, xcd=blockIdx&7) reads its 2048-edge chunk and handles ONLY
// dsts in [xcd*NPX, (xcd+1)*NPX). blockIdx%8 ~ XCD (dispatch round-robin) => deg/csr lines
// are single-XCD: atomics hit locally-owned L2 lines, each line written back to HBM once.
__global__ void k_build(const int* __restrict__ src, const int* __restrict__ dst,
                        int* __restrict__ degPad, u16* __restrict__ csrPad,
                        const float* __restrict__ x, __hip_bfloat162* __restrict__ xb2,
                        const float* __restrict__ W1l, const float* __restrict__ W1r,
                        const float* __restrict__ W2l, const float* __restrict__ W2r,
                        bf16* __restrict__ W1b, bf16* __restrict__ W2b) {
    int b = blockIdx.x;
    if (b < SCAT_BLKS) {
        int chunk = b >> 3;
        int lo = (b & 7) * NPX, hi = lo + NPX;
        int e0 = chunk * ECHUNK + threadIdx.x * 8;
        if (e0 + 7 < NE) {                        // 8 | NE: per-thread all-or-nothing
            int4 d0 = *(const int4*)(dst + e0);
            int4 d1 = *(const int4*)(dst + e0 + 4);
            int4 s0 = *(const int4*)(src + e0);
            int4 s1 = *(const int4*)(src + e0 + 4);
            int dv[8] = {d0.x, d0.y, d0.z, d0.w, d1.x, d1.y, d1.z, d1.w};
            int sv[8] = {s0.x, s0.y, s0.z, s0.w, s1.x, s1.y, s1.z, s1.w};
            #pragma unroll
            for (int j = 0; j < 8; ++j) {
                int t = dv[j];
                if (t >= lo && t < hi) {          // XCD-range filter (also poison filter)
                    int pos = atomicAdd(&degPad[t * DSTRIDE], 1);
                    if (pos < CAP) csrPad[t * CAP + pos] = (u16)sv[j];
                }
            }
        }
    } else if (b < SCAT_BLKS + 6250) {            // N*DIN/4 = 1.6M float4 groups exactly
        int i = (b - SCAT_BLKS) * 256 + threadIdx.x;
        float4 v = ((const float4*)x)[i];
        __hip_bfloat162 a, bb;
        a.x = __float2bfloat16(v.x); a.y = __float2bfloat16(v.y);
        bb.x = __float2bfloat16(v.z); bb.y = __float2bfloat16(v.w);
        xb2[2 * i]     = a;
        xb2[2 * i + 1] = bb;
    } else {                                      // 192 blocks: 32768 + 16384 weights exactly
        int i = (b - SCAT_BLKS - 6250) * 256 + threadIdx.x;
        if (i < 128 * 256) {
            int n = i >> 8, k = i & 255;
            float v = (k < 128) ? W1l[n * 128 + k] : W1r[n * 128 + (k - 128)];
            W1b[i] = __float2bfloat16(v);
        } else {
            int j = i - 128 * 256;
            int n = j >> 7, k = j & 127;
            float v = (n < 64) ? W2l[n * 128 + k] : W2r[(n - 64) * 128 + k];
            W2b[j] = __float2bfloat16(v);
        }
    }
}

// ---------------- layer-1 aggregation: index-prefetch + batched gathers ----------------
// lane = g*16 + c : g = neighbor slot (0-3), c = 16B chunk (0-15) of the 256B xb row.
// All csr indices load upfront (independent, one 128B line), then all row-gathers issue
// back-to-back under uniform branches: chain = csr_latency + gather_latency, not per-iter.
__global__ __launch_bounds__(256) void k_agg1(const int* __restrict__ degPad, const u16* __restrict__ csrPad,
                                              const short* __restrict__ xb,
                                              short* __restrict__ msg) {
    int node = blockIdx.x * 4 + (threadIdx.x >> 6);
    if (node >= N_NODES) return;
    int lane = threadIdx.x & 63;
    int g = lane >> 4, c = lane & 15;
    int d = min(max(degPad[node * DSTRIDE], 0), CAP);   // poison-robust
    const u16* crow = csrPad + node * CAP;
    int idx[8];                                   // slots g, 4+g, ..., 28+g (covers d<=32)
    #pragma unroll
    for (int t = 0; t < 8; ++t) idx[t] = crow[t * 4 + g];
    float acc[8];
    #pragma unroll
    for (int j = 0; j < 8; ++j) acc[j] = 0.f;
    short8 v[8];
    #pragma unroll
    for (int t = 0; t < 8; ++t) {                 // issue ALL gathers before any accumulate
        if (4 * t < d) {
            int n = clamp_node(idx[t]);
            v[t] = *(const short8*)(xb + (size_t)n * DIN + c * 8);
        }
    }
    #pragma unroll
    for (int t = 0; t < 8; ++t) {
        if (4 * t < d) {
            if (4 * t + g < d) {                  // per-lane valid only in final group
                #pragma unroll
                for (int j = 0; j < 8; ++j) acc[j] += b2f(v[t][j]);
            }
        }
    }
    if (d > 32) {                                 // rare (P ~ 1e-4 per node), wave-uniform
        int idxh[8];
        #pragma unroll
        for (int t = 8; t < 16; ++t) idxh[t - 8] = crow[t * 4 + g];
        short8 vh[8];
        #pragma unroll
        for (int t = 8; t < 16; ++t) {
            if (4 * t < d) {
                int n = clamp_node(idxh[t - 8]);
                vh[t - 8] = *(const short8*)(xb + (size_t)n * DIN + c * 8);
            }
        }
        #pragma unroll
        for (int t = 8; t < 16; ++t) {
            if (4 * t < d) {
                if (4 * t + g < d) {
                    #pragma unroll
                    for (int j = 0; j < 8; ++j) acc[j] += b2f(vh[t - 8][j]);
                }
            }
        }
    }
    #pragma unroll
    for (int j = 0; j < 8; ++j) {                 // reduce across the 4 neighbor slots
        acc[j] += __shfl_xor(acc[j], 16);
        acc[j] += __shfl_xor(acc[j], 32);
    }
    if (g == 0) {
        float inv = (d > 0) ? 1.0f / (float)d : 0.0f;
        short8 o;
        #pragma unroll
        for (int j = 0; j < 8; ++j) o[j] = f2b(acc[j] * inv);
        *(short8*)(msg + (size_t)node * DIN + c * 8) = o;
    }
}

// ---------------- fused MFMA: h-tile = relu([msg|xb]@W1b^T + b1) in LDS, then [pb|q] = h@W2b^T ----------------
__global__ __launch_bounds__(256) void k_mfma12(const short* __restrict__ msg,
                                                const short* __restrict__ xb,
                                                const short* __restrict__ W1b,
                                                const float* __restrict__ b1,
                                                const short* __restrict__ W2b,
                                                bf16* __restrict__ pb,
                                                float* __restrict__ qbuf) {
    __shared__ short hs[16][136];                 // 16-row h tile, +8 pad spreads banks
    int wave = threadIdx.x >> 6, lane = threadIdx.x & 63;
    int q = lane >> 4, mr = lane & 15;
    int n0 = wave * 32;
    short8 Bf1[2][8];
    #pragma unroll
    for (int t = 0; t < 2; ++t) {
        const short* wrow = W1b + (size_t)(n0 + t * 16 + mr) * 256 + q * 8;
        #pragma unroll
        for (int ks = 0; ks < 8; ++ks) Bf1[t][ks] = *(const short8*)(wrow + ks * 32);
    }
    short8 Bf2[2][4];
    #pragma unroll
    for (int t = 0; t < 2; ++t) {
        const short* wrow = W2b + (size_t)(n0 + t * 16 + mr) * 128 + q * 8;
        #pragma unroll
        for (int ks = 0; ks < 4; ++ks) Bf2[t][ks] = *(const short8*)(wrow + ks * 32);
    }
    float bias0 = b1[n0 + mr], bias1 = b1[n0 + 16 + mr];
    for (int mt = blockIdx.x; mt < MTILES; mt += gridDim.x) {
        // ---- GEMM1: 16 rows x 32 cols per wave, K=256 over [msg|xb] ----
        const short* a0 = msg + (size_t)(mt * 16 + mr) * DIN + q * 8;
        const short* a1 = xb  + (size_t)(mt * 16 + mr) * DIN + q * 8;
        short8 Af[8];
        #pragma unroll
        for (int ks = 0; ks < 4; ++ks) Af[ks]     = *(const short8*)(a0 + ks * 32);
        #pragma unroll
        for (int ks = 0; ks < 4; ++ks) Af[4 + ks] = *(const short8*)(a1 + ks * 32);
        f32x4 acc0 = {0.f, 0.f, 0.f, 0.f}, acc1 = {0.f, 0.f, 0.f, 0.f};
        #pragma unroll
        for (int ks = 0; ks < 8; ++ks) {
            acc0 = __builtin_amdgcn_mfma_f32_16x16x32_bf16(Af[ks], Bf1[0][ks], acc0, 0, 0, 0);
            acc1 = __builtin_amdgcn_mfma_f32_16x16x32_bf16(Af[ks], Bf1[1][ks], acc1, 0, 0, 0);
        }
        __syncthreads();                          // prior iteration's hs reads complete
        #pragma unroll
        for (int r = 0; r < 4; ++r) {             // bias + relu, stage h tile to LDS (C/D layout)
            int row = q * 4 + r;
            float v0 = acc0[r] + bias0;
            float v1 = acc1[r] + bias1;
            hs[row][n0 + mr]      = f2b(v0 > 0.f ? v0 : 0.f);
            hs[row][n0 + 16 + mr] = f2b(v1 > 0.f ? v1 : 0.f);
        }
        __syncthreads();                          // hs tile complete
        // ---- GEMM2: A from LDS (row mr, 16B contiguous), K=128 ----
        short8 Ah[4];
        #pragma unroll
        for (int ks = 0; ks < 4; ++ks) Ah[ks] = *(const short8*)(&hs[mr][ks * 32 + q * 8]);
        f32x4 c20 = {0.f, 0.f, 0.f, 0.f}, c21 = {0.f, 0.f, 0.f, 0.f};
        #pragma unroll
        for (int ks = 0; ks < 4; ++ks) {
            c20 = __builtin_amdgcn_mfma_f32_16x16x32_bf16(Ah[ks], Bf2[0][ks], c20, 0, 0, 0);
            c21 = __builtin_amdgcn_mfma_f32_16x16x32_bf16(Ah[ks], Bf2[1][ks], c21, 0, 0, 0);
        }
        // cols: waves 0,1 -> pb (0-63) bf16; waves 2,3 -> q (64-127) fp32. Wave-uniform branch.
        #pragma unroll
        for (int r = 0; r < 4; ++r) {
            int row = mt * 16 + q * 4 + r;
            int c0 = n0 + mr, c1 = n0 + 16 + mr;
            if (c0 < 64) {
                pb[(size_t)row * 64 + c0] = __float2bfloat16(c20[r]);
                pb[(size_t)row * 64 + c1] = __float2bfloat16(c21[r]);
            } else {
                qbuf[(size_t)row * 64 + (c0 - 64)] = c20[r];
                qbuf[(size_t)row * 64 + (c1 - 64)] = c21[r];
            }
        }
    }
}

// ---------------- layer-2 aggregation + epilogue: 2 nodes per wave for 2x gather MLP ----------------
// lane = g*8 + c : g = neighbor slot (0-7), c = 16B chunk (0-7) of the 128B pb row.
// Typical deg~16 gives only 2 in-flight gathers per node; interleaving two independent
// nodes per wave doubles in-flight loads on the latency-critical path (deg/csr lines pair too).
__global__ __launch_bounds__(256) void k_agg2f(const int* __restrict__ degPad, const u16* __restrict__ csrPad,
                                               const short* __restrict__ pb, const float* __restrict__ qbuf,
                                               const float* __restrict__ b2, float* __restrict__ out) {
    int wave = threadIdx.x >> 6;
    int nA = blockIdx.x * 8 + wave * 2;           // this wave's node pair: nA, nA+1
    if (nA >= N_NODES) return;
    int nB = nA + 1;                              // N even => nB < N_NODES always
    int lane = threadIdx.x & 63;
    int g = lane >> 3, c = lane & 7;
    int dA = min(max(degPad[nA * DSTRIDE], 0), CAP);   // poison-robust
    int dB = min(max(degPad[nB * DSTRIDE], 0), CAP);
    const u16* crA = csrPad + nA * CAP;
    const u16* crB = csrPad + nB * CAP;
    int idxA[4], idxB[4];                         // slots g, 8+g, 16+g, 24+g (covers d<=32)
    #pragma unroll
    for (int t = 0; t < 4; ++t) idxA[t] = crA[t * 8 + g];
    #pragma unroll
    for (int t = 0; t < 4; ++t) idxB[t] = crB[t * 8 + g];
    float accA[8], accB[8];
    #pragma unroll
    for (int j = 0; j < 8; ++j) { accA[j] = 0.f; accB[j] = 0.f; }
    short8 vA[4], vB[4];
    #pragma unroll
    for (int t = 0; t < 4; ++t) {                 // issue ALL gathers (both nodes) before accumulate
        if (8 * t < dA) vA[t] = *(const short8*)(pb + (size_t)clamp_node(idxA[t]) * 64 + c * 8);
    }
    #pragma unroll
    for (int t = 0; t < 4; ++t) {
        if (8 * t < dB) vB[t] = *(const short8*)(pb + (size_t)clamp_node(idxB[t]) * 64 + c * 8);
    }
    #pragma unroll
    for (int t = 0; t < 4; ++t) {
        if (8 * t < dA) {
            if (8 * t + g < dA) {
                #pragma unroll
                for (int j = 0; j < 8; ++j) accA[j] += b2f(vA[t][j]);
            }
        }
    }
    #pragma unroll
    for (int t = 0; t < 4; ++t) {
        if (8 * t < dB) {
            if (8 * t + g < dB) {
                #pragma unroll
                for (int j = 0; j < 8; ++j) accB[j] += b2f(vB[t][j]);
            }
        }
    }
    if (dA > 32) {                                // rare, wave-uniform
        #pragma unroll
        for (int t = 4; t < 8; ++t) {
            if (8 * t < dA) {
                int n = clamp_node(crA[t * 8 + g]);
                short8 v = *(const short8*)(pb + (size_t)n * 64 + c * 8);
                if (8 * t + g < dA) {
                    #pragma unroll
                    for (int j = 0; j < 8; ++j) accA[j] += b2f(v[j]);
                }
            }
        }
    }
    if (dB > 32) {                                // rare, wave-uniform
        #pragma unroll
        for (int t = 4; t < 8; ++t) {
            if (8 * t < dB) {
                int n = clamp_node(crB[t * 8 + g]);
                short8 v = *(const short8*)(pb + (size_t)n * 64 + c * 8);
                if (8 * t + g < dB) {
                    #pragma unroll
                    for (int j = 0; j < 8; ++j) accB[j] += b2f(v[j]);
                }
            }
        }
    }
    #pragma unroll
    for (int j = 0; j < 8; ++j) {                 // reduce across the 8 neighbor slots
        accA[j] += __shfl_xor(accA[j], 8);
        accA[j] += __shfl_xor(accA[j], 16);
        accA[j] += __shfl_xor(accA[j], 32);
        accB[j] += __shfl_xor(accB[j], 8);
        accB[j] += __shfl_xor(accB[j], 16);
        accB[j] += __shfl_xor(accB[j], 32);
    }
    if (g == 0) {                                 // lanes 0-7: write both rows (chunk = c)
        {
            float inv = (dA > 0) ? 1.0f / (float)dA : 0.0f;
            const float* qr = qbuf + (size_t)nA * 64 + c * 8;
            const float* br = b2 + c * 8;
            float* orow = out + (size_t)nA * 64 + c * 8;
            float4 o0, o1;
            o0.x = accA[0] * inv + qr[0] + br[0];
            o0.y = accA[1] * inv + qr[1] + br[1];
            o0.z = accA[2] * inv + qr[2] + br[2];
            o0.w = accA[3] * inv + qr[3] + br[3];
            o1.x = accA[4] * inv + qr[4] + br[4];
            o1.y = accA[5] * inv + qr[5] + br[5];
            o1.z = accA[6] * inv + qr[6] + br[6];
            o1.w = accA[7] * inv + qr[7] + br[7];
            ((float4*)orow)[0] = o0;
            ((float4*)orow)[1] = o1;
        }
        {
            float inv = (dB > 0) ? 1.0f / (float)dB : 0.0f;
            const float* qr = qbuf + (size_t)nB * 64 + c * 8;
            const float* br = b2 + c * 8;
            float* orow = out + (size_t)nB * 64 + c * 8;
            float4 o0, o1;
            o0.x = accB[0] * inv + qr[0] + br[0];
            o0.y = accB[1] * inv + qr[1] + br[1];
            o0.z = accB[2] * inv + qr[2] + br[2];
            o0.w = accB[3] * inv + qr[3] + br[3];
            o1.x = accB[4] * inv + qr[4] + br[4];
            o1.y = accB[5] * inv + qr[5] + br[5];
            o1.z = accB[6] * inv + qr[6] + br[6];
            o1.w = accB[7] * inv + qr[7] + br[7];
            ((float4*)orow)[0] = o0;
            ((float4*)orow)[1] = o1;
        }
    }
}

extern "C" void kernel_launch(void* const* d_in, const int* in_sizes, int n_in,
                              void* d_out, int out_size, void* d_ws, size_t ws_size,
                              hipStream_t stream) {
    const float* x   = (const float*)d_in[0];
    const int*   ei  = (const int*)  d_in[1];
    const float* W1l = (const float*)d_in[2];
    const float* b1  = (const float*)d_in[3];
    const float* W1r = (const float*)d_in[4];
    const float* W2l = (const float*)d_in[5];
    const float* b2  = (const float*)d_in[6];
    const float* W2r = (const float*)d_in[7];
    float* out = (float*)d_out;

    const int* src = ei;        // edge_index[0]
    const int* dst = ei + NE;   // edge_index[1]

    // workspace layout (bytes), ~52.9 MB:
    //   [0, 1600000)            degPad (N*8 ints, 4 nodes per 128B line)
    //   [1600000, 8000000)      csrPad (N*64 ushort)
    //   [8000000, 20800000)     xb  bf16 (N*128*2)
    //   [20800000, 33600000)    msg bf16 (N*128*2)
    //   [33600000, 40000000)    pb  bf16 (N*64*2)
    //   [40000000, 52800000)    qbuf fp32 (N*64*4)
    //   [52800000, 52865536)    W1b bf16 (128*256*2)
    //   [52865536, 52898304)    W2b bf16 (128*128*2)
    char* ws = (char*)d_ws;
    int*   degPad = (int*)  (ws + 0);
    u16*   csrPad = (u16*)  (ws + 1600000);
    short* xb     = (short*)(ws + 8000000);
    short* msg    = (short*)(ws + 20800000);
    bf16*  pb     = (bf16*) (ws + 33600000);
    float* qbuf   = (float*)(ws + 40000000);
    bf16*  W1b    = (bf16*) (ws + 52800000);
    bf16*  W2b    = (bf16*) (ws + 52865536);

    hipMemsetAsync(degPad, 0, 1600000, stream);

    k_build<<<SCAT_BLKS + 6250 + 192, 256, 0, stream>>>(src, dst, degPad, csrPad,
                                                        x, (__hip_bfloat162*)xb,
                                                        W1l, W1r, W2l, W2r, W1b, W2b);
    k_agg1<<<(N_NODES + 3) / 4, 256, 0, stream>>>(degPad, csrPad, xb, msg);
    k_mfma12<<<512, 256, 0, stream>>>(msg, xb, (const short*)W1b, b1, (const short*)W2b, pb, qbuf);
    k_agg2f<<<(N_NODES + 7) / 8, 256, 0, stream>>>(degPad, csrPad, (const short*)pb, qbuf, b2, out);
}